// Round 4
// baseline (373.980 us; speedup 1.0000x reference)
//
#include <hip/hip_runtime.h>
#include <stdint.h>

// ---------------------------------------------------------------------------
// SparseResUQueryNet: bitmap+rank sparse conv -> time max-pool -> sparse conv
//
// Round-12 = round-11 (verified 283.6us) + 2-point software pipelining in
// both hot kernels:
//   - each half-wave now owns TWO consecutive points/voxels; all scattered
//     probe loads (bm+rank for A and B) issue before either is consumed,
//     and query's hit-loop is fused so A/B pooled-row gathers overlap.
//     Rationale: both kernels are dependent-latency bound at HW-max waves
//     (VGPR 32/12 << 64-VGPR cliff) — only per-wave MLP can increase
//     in-flight scattered loads. Rounds 9/10 lesson respected: VGPR stays
//     <64 (predict ~44 query / ~24 bb_pool), occupancy unchanged.
//   - everything else (27-lane parallel probe, float2 stores, memset cut,
//     zero_multi, split bm/rank, bf16 monotone pooled) verified round-11.
// ---------------------------------------------------------------------------

#define TPB 256
#define SCAN_WPT 8
typedef unsigned long long u64;
typedef unsigned int u32;
typedef unsigned short u16;

// f32 -> RNE bf16 -> monotone u16 (order-preserving; 0 is below all reals)
__device__ __forceinline__ u32 trans16(float x) {
    u32 b = __float_as_uint(x);
    u32 bf = (b + 0x7FFFu + ((b >> 16) & 1u)) >> 16;
    return ((bf & 0x8000u) ? (~bf) : (bf | 0x8000u)) & 0xFFFFu;
}
__device__ __forceinline__ float detrans16(u32 u) {
    u32 orig = (u & 0x8000u) ? (u & 0x7FFFu) : ((~u) & 0xFFFFu);
    return __uint_as_float(orig << 16);
}

// K1: set existence bits; second pool contributor marks multi ----------------
__global__ void build_bitmaps_kernel(const int4* __restrict__ hc,
                                     const int* __restrict__ hb,
                                     int n,
                                     u64* __restrict__ hist_bm,
                                     u64* __restrict__ pool_bm,
                                     u64* __restrict__ multi_bm) {
    int j = blockIdx.x * blockDim.x + threadIdx.x;
    if (j >= n) return;
    int4 c = hc[j];                                   // (t,x,y,z)
    int key = ((c.x * 256 + c.y) * 256 + c.z) * 256 + c.w;
    atomicOr(&hist_bm[key >> 6], 1ull << (key & 63));
    int pk = ((hb[j] * 256 + c.y) * 256 + c.z) * 256 + c.w;
    u64 bit = 1ull << (pk & 63);
    u64 old = atomicOr(&pool_bm[pk >> 6], bit);
    if (old & bit) atomicOr(&multi_bm[pk >> 6], bit); // >=2 contributors
}

// scan stage 1: per-block popcount sums --------------------------------------
__global__ void scan_sum_kernel(const u64* __restrict__ bm, u32* __restrict__ bsum) {
    __shared__ u32 s[TPB];
    int t = threadIdx.x;
    size_t base = ((size_t)blockIdx.x * TPB + t) * SCAN_WPT;
    u32 acc = 0;
#pragma unroll
    for (int i = 0; i < SCAN_WPT; i++) acc += __popcll(bm[base + i]);
    s[t] = acc; __syncthreads();
    for (int off = TPB / 2; off > 0; off >>= 1) {
        if (t < off) s[t] += s[t + off];
        __syncthreads();
    }
    if (t == 0) bsum[blockIdx.x] = s[0];
}

// scan stage 2: exclusive scan of block sums (count <= 2048), one block ------
__global__ void scan_partials_kernel(u32* __restrict__ bsum, int count) {
    __shared__ u32 s[TPB];
    int t = threadIdx.x;
    int wpt = count >> 8;                              // 8 (hist) or 1 (pool)
    u32 v[8]; u32 acc = 0;
    for (int i = 0; i < wpt; i++) { v[i] = bsum[t * wpt + i]; acc += v[i]; }
    s[t] = acc; __syncthreads();
    for (int off = 1; off < TPB; off <<= 1) {          // inclusive Hillis-Steele
        u32 x = (t >= off) ? s[t - off] : 0;
        __syncthreads();
        s[t] += x;
        __syncthreads();
    }
    u32 run = s[t] - acc;                              // exclusive base
    for (int i = 0; i < wpt; i++) { bsum[t * wpt + i] = run; run += v[i]; }
}

// scan stage 3: per-word exclusive rank --------------------------------------
__global__ void scan_apply_kernel(const u64* __restrict__ bm,
                                  const u32* __restrict__ bsum,
                                  u32* __restrict__ rank) {
    __shared__ u32 s[TPB];
    int t = threadIdx.x;
    size_t base = ((size_t)blockIdx.x * TPB + t) * SCAN_WPT;
    u32 pc[SCAN_WPT]; u32 acc = 0;
#pragma unroll
    for (int i = 0; i < SCAN_WPT; i++) { pc[i] = __popcll(bm[base + i]); acc += pc[i]; }
    s[t] = acc; __syncthreads();
    for (int off = 1; off < TPB; off <<= 1) {
        u32 x = (t >= off) ? s[t - off] : 0;
        __syncthreads();
        s[t] += x;
        __syncthreads();
    }
    u32 run = bsum[blockIdx.x] + s[t] - acc;
#pragma unroll
    for (int i = 0; i < SCAN_WPT; i++) { rank[base + i] = run; run += pc[i]; }
}

// zero only the pooled rows that will take the CAS-max path ------------------
__global__ void zero_multi_kernel(const u64* __restrict__ multi_bm,
                                  const u64* __restrict__ pool_bm,
                                  const u32* __restrict__ pool_rank,
                                  u32* __restrict__ pooled) {
    int wI = blockIdx.x * blockDim.x + threadIdx.x;    // word index < NW_P
    u64 mw = multi_bm[wI];
    if (!mw) return;
    u64 pw = pool_bm[wI];
    u32 rb = pool_rank[wI];
    while (mw) {
        int b = __ffsll((long long)mw) - 1;
        mw &= mw - 1;
        u32 slot = rb + (u32)__popcll(pw & ((1ull << b) - 1ull));
        u32* row = pooled + (size_t)slot * 16;
#pragma unroll
        for (int i = 0; i < 16; i++) row[i] = 0u;
    }
}

// K2: half-wave per TWO voxels: 27-tap conv (1->32) + packed pooled write ----
__global__ __launch_bounds__(TPB, 8)
void bb_pool_kernel(const int4* __restrict__ hc,
                    const int* __restrict__ hb,
                    const float* __restrict__ hf,
                    const float* __restrict__ Wbb,   // [27*32]
                    int n,
                    const u64* __restrict__ hist_bm,
                    const u32* __restrict__ hist_rank,
                    const u64* __restrict__ pool_bm,
                    const u32* __restrict__ pool_rank,
                    const u64* __restrict__ multi_bm,
                    u32* __restrict__ pooled) {
    int h = (blockIdx.x * blockDim.x + threadIdx.x) >> 5;   // half-wave index
    int pA = h * 2, pB = pA + 1;
    if (pA >= n) return;
    bool hasB = (pB < n);
    int lane = threadIdx.x & 63;
    int hb32 = lane & 32;                              // half base within wave
    int f = lane & 31;                                 // feature / tap lane

    int4 cA = hc[pA];
    int4 cB = hc[hasB ? pB : pA];
    int bA = hb[pA];
    int bB = hb[hasB ? pB : pA];
    int kA = ((cA.x * 256 + cA.y) * 256 + cA.z) * 256 + cA.w;
    int kB = ((cB.x * 256 + cB.y) * 256 + cB.z) * 256 + cB.w;
    int pkA = ((bA * 256 + cA.y) * 256 + cA.z) * 256 + cA.w;
    int pkB = ((bB * 256 + cB.y) * 256 + cB.z) * 256 + cB.w;

    // pool-side loads issued early (independent of probe chain)
    u64 pwA = pool_bm[pkA >> 6];
    u32 prA = pool_rank[pkA >> 6];
    u64 mwA = multi_bm[pkA >> 6];
    u64 pwB = pool_bm[pkB >> 6];
    u32 prB = pool_rank[pkB >> 6];
    u64 mwB = multi_bm[pkB >> 6];

    float fvA = 0.f, fvB = 0.f;
    bool hitA = false, hitB = false;
    if (f < 27) {
        int t1 = f / 9, rem = f - t1 * 9, t2 = rem / 3, t3 = rem - t2 * 3;
        int d = (t1 - 1) * 65536 + (t2 - 1) * 256 + (t3 - 1);
        int nA = kA + d, nB = kB + d;
        // 4 independent scattered loads, all in flight together
        u64 wA = hist_bm[nA >> 6];
        u32 rA = hist_rank[nA >> 6];
        u64 wB = hist_bm[nB >> 6];
        u32 rB = hist_rank[nB >> 6];
        if ((wA >> (nA & 63)) & 1ull) {
            u32 r = rA + (u32)__popcll(wA & ((1ull << (nA & 63)) - 1ull));
            fvA = hf[r]; hitA = true;
        }
        if ((wB >> (nB & 63)) & 1ull) {
            u32 r = rB + (u32)__popcll(wB & ((1ull << (nB & 63)) - 1ull));
            fvB = hf[r]; hitB = true;
        }
    }
    u32 mAm = (u32)(__ballot(hitA) >> hb32);
    u32 mBm = (u32)(__ballot(hitB) >> hb32);

    float accA = 0.f, accB = 0.f;
    while (mAm) {
        int b = __ffs(mAm) - 1; mAm &= mAm - 1;
        float fb = __shfl(fvA, hb32 + b);
        accA = fmaf(fb, Wbb[b * 32 + f], accA);        // L1-hot 3.4KB table
    }
    while (mBm) {
        int b = __ffs(mBm) - 1; mBm &= mBm - 1;
        float fb = __shfl(fvB, hb32 + b);
        accB = fmaf(fb, Wbb[b * 32 + f], accB);
    }

    // ---- store A ----
    {
        int bit = pkA & 63;
        int slot = (int)(prA + (u32)__popcll(pwA & ((1ull << bit) - 1ull)));
        bool multi = (mwA >> bit) & 1ull;
        u32 tv = trans16(accA);
        u32 packed = tv | (((u32)__shfl_down((int)tv, 1)) << 16);
        if ((f & 1) == 0) {
            u32* addr = pooled + (size_t)slot * 16 + (f >> 1);
            if (!multi) {
                *addr = packed;
            } else {
                u32 oldv = *addr;
                while (true) {
                    u32 lo = max(oldv & 0xFFFFu, packed & 0xFFFFu);
                    u32 hi = max(oldv >> 16, packed >> 16);
                    u32 mx = lo | (hi << 16);
                    if (mx == oldv) break;
                    u32 prev = atomicCAS(addr, oldv, mx);
                    if (prev == oldv) break;
                    oldv = prev;
                }
            }
        }
    }
    // ---- store B ----
    if (hasB) {
        int bit = pkB & 63;
        int slot = (int)(prB + (u32)__popcll(pwB & ((1ull << bit) - 1ull)));
        bool multi = (mwB >> bit) & 1ull;
        u32 tv = trans16(accB);
        u32 packed = tv | (((u32)__shfl_down((int)tv, 1)) << 16);
        if ((f & 1) == 0) {
            u32* addr = pooled + (size_t)slot * 16 + (f >> 1);
            if (!multi) {
                *addr = packed;
            } else {
                u32 oldv = *addr;
                while (true) {
                    u32 lo = max(oldv & 0xFFFFu, packed & 0xFFFFu);
                    u32 hi = max(oldv >> 16, packed >> 16);
                    u32 mx = lo | (hi << 16);
                    if (mx == oldv) break;
                    u32 prev = atomicCAS(addr, oldv, mx);
                    if (prev == oldv) break;
                    oldv = prev;
                }
            }
        }
    }
}

// K3: half-wave per TWO query points: 27-tap conv (32->32) + output ---------
__global__ __launch_bounds__(TPB, 8)
void query_kernel(const int4* __restrict__ qc,
                  const float* __restrict__ pts,      // stride 5
                  const float* __restrict__ Wc,       // [27][32][32]
                  int m,
                  const u64* __restrict__ pool_bm,
                  const u32* __restrict__ pool_rank,
                  const u16* __restrict__ pooled16,
                  float* __restrict__ out) {
    int h = (blockIdx.x * blockDim.x + threadIdx.x) >> 5;
    int pA = h * 2, pB = pA + 1;
    if (pA >= m) return;
    bool hasB = (pB < m);
    int lane = threadIdx.x & 63;
    int hb32 = lane & 32;
    int f = lane & 31;

    int4 cA = qc[pA];
    int4 cB = qc[hasB ? pB : pA];
    int kA = ((cA.x * 256 + cA.y) * 256 + cA.z) * 256 + cA.w;
    int kB = ((cB.x * 256 + cB.y) * 256 + cB.z) * 256 + cB.w;

    int slA = -1, slB = -1;
    if (f < 27) {
        int t1 = f / 9, rem = f - t1 * 9, t2 = rem / 3, t3 = rem - t2 * 3;
        int d = (t1 - 1) * 65536 + (t2 - 1) * 256 + (t3 - 1);
        int nA = kA + d, nB = kB + d;
        // 4 independent scattered loads, all in flight together
        u64 wA = pool_bm[nA >> 6];
        u32 rA = pool_rank[nA >> 6];
        u64 wB = pool_bm[nB >> 6];
        u32 rB = pool_rank[nB >> 6];
        if ((wA >> (nA & 63)) & 1ull)
            slA = (int)(rA + (u32)__popcll(wA & ((1ull << (nA & 63)) - 1ull)));
        if (hasB && ((wB >> (nB & 63)) & 1ull))
            slB = (int)(rB + (u32)__popcll(wB & ((1ull << (nB & 63)) - 1ull)));
    }
    u32 mAm = (u32)(__ballot(slA >= 0) >> hb32);
    u32 mBm = (u32)(__ballot(slB >= 0) >> hb32);

    float accA = 0.f, accB = 0.f;
    // fused loop: A's and B's pooled-row gathers issue together (MLP x2)
    while (mAm | mBm) {
        int tA = -1, tB = -1;
        float pvA = 0.f, pvB = 0.f;
        if (mAm) {
            tA = __ffs(mAm) - 1; mAm &= mAm - 1;
            int slot = __shfl(slA, hb32 + tA);
            pvA = detrans16(pooled16[(size_t)slot * 32 + f]);  // 64B row
        }
        if (mBm) {
            tB = __ffs(mBm) - 1; mBm &= mBm - 1;
            int slot = __shfl(slB, hb32 + tB);
            pvB = detrans16(pooled16[(size_t)slot * 32 + f]);
        }
        if (tA >= 0) {
            const float* W = Wc + tA * 1024 + f;       // W[b][k][f], k-major
#pragma unroll
            for (int k = 0; k < 32; k++) {
                float pk_ = __shfl(pvA, hb32 + k);     // broadcast P[k]
                accA = fmaf(pk_, W[k * 32], accA);     // coalesced 128B W line
            }
        }
        if (tB >= 0) {
            const float* W = Wc + tB * 1024 + f;
#pragma unroll
            for (int k = 0; k < 32; k++) {
                float pk_ = __shfl(pvB, hb32 + k);
                accB = fmaf(pk_, W[k * 32], accB);
            }
        }
    }

    // paired float2 stores: 16 store lane-requests per point instead of 32
    float a2 = __shfl_down(accA, 1);
    float b2 = __shfl_down(accB, 1);
    if ((f & 1) == 0) {
        float2 st; st.x = accA; st.y = a2;
        *(float2*)(out + (size_t)pA * 36 + 4 + f) = st;
        if (hasB) {
            float2 st2; st2.x = accB; st2.y = b2;
            *(float2*)(out + (size_t)pB * 36 + 4 + f) = st2;
        }
    }
    if (f < 4) {
        out[(size_t)pA * 36 + f] = pts[pA * 5 + f];
        if (hasB) out[(size_t)pB * 36 + f] = pts[pB * 5 + f];
    }
}

// ---------------------------------------------------------------------------
extern "C" void kernel_launch(void* const* d_in, const int* in_sizes, int n_in,
                              void* d_out, int out_size, void* d_ws, size_t ws_size,
                              hipStream_t stream) {
    const float* hfeat   = (const float*)d_in[0];   // [n,1]
    const float* pts     = (const float*)d_in[1];   // [m,5]
    const float* Wbb     = (const float*)d_in[2];   // [27,1,32]
    const float* Wconv   = (const float*)d_in[3];   // [27,32,32]
    const int4*  hcoords = (const int4*)d_in[4];    // [n,4] sorted by packed key
    const int*   hbatch  = (const int*)d_in[5];     // [n]
    const int4*  qcoords = (const int4*)d_in[6];    // [m,4]
    int n = in_sizes[0];
    int m = in_sizes[1] / 5;

    const int NW_H = 1 << 22;                       // 2^28 bits / 64
    const int NW_P = 1 << 19;                       // 2^25 bits / 64
    const int GB_H = NW_H / (TPB * SCAN_WPT);       // 2048
    const int GB_P = NW_P / (TPB * SCAN_WPT);       // 256

    // layout: [hist_bm | pool_bm | multi_bm] zeroed; pooled NOT zeroed
    char* w = (char*)d_ws;
    char* zbase = w;
    u64* hist_bm      = (u64*)w;       w += (size_t)NW_H * 8;
    u64* pool_bm      = (u64*)w;       w += (size_t)NW_P * 8;
    u64* multi_bm     = (u64*)w;       w += (size_t)NW_P * 8;
    size_t zbytes = (size_t)(w - zbase);
    u32* pooled       = (u32*)w;       w += (size_t)n * 64;      // 16 u32/slot
    u32* hist_rank    = (u32*)w;       w += (size_t)NW_H * 4;
    u32* pool_rank    = (u32*)w;       w += (size_t)NW_P * 4;
    u32* bsum_h       = (u32*)w;       w += (size_t)GB_H * 4;
    u32* bsum_p       = (u32*)w;

    hipMemsetAsync(zbase, 0x00, zbytes, stream);

    int gb_n   = (n + TPB - 1) / TPB;
    // 2 points per half-wave: 32 threads per pair
    long long halvesN = (n + 1) / 2;
    long long halvesM = ((long long)m + 1) / 2;
    int gb_n16 = (int)((halvesN * 32 + TPB - 1) / TPB);
    int gb_m16 = (int)((halvesM * 32 + TPB - 1) / TPB);

    build_bitmaps_kernel<<<gb_n, TPB, 0, stream>>>(hcoords, hbatch, n,
                                                   hist_bm, pool_bm, multi_bm);
    scan_sum_kernel<<<GB_H, TPB, 0, stream>>>(hist_bm, bsum_h);
    scan_partials_kernel<<<1, TPB, 0, stream>>>(bsum_h, GB_H);
    scan_apply_kernel<<<GB_H, TPB, 0, stream>>>(hist_bm, bsum_h, hist_rank);
    scan_sum_kernel<<<GB_P, TPB, 0, stream>>>(pool_bm, bsum_p);
    scan_partials_kernel<<<1, TPB, 0, stream>>>(bsum_p, GB_P);
    scan_apply_kernel<<<GB_P, TPB, 0, stream>>>(pool_bm, bsum_p, pool_rank);
    zero_multi_kernel<<<NW_P / TPB, TPB, 0, stream>>>(multi_bm, pool_bm,
                                                      pool_rank, pooled);
    bb_pool_kernel<<<gb_n16, TPB, 0, stream>>>(hcoords, hbatch, hfeat, Wbb, n,
                                               hist_bm, hist_rank,
                                               pool_bm, pool_rank, multi_bm, pooled);
    query_kernel<<<gb_m16, TPB, 0, stream>>>(qcoords, pts, Wconv, m,
                                             pool_bm, pool_rank,
                                             (const u16*)pooled, (float*)d_out);
}

// Round 5
// 279.719 us; speedup vs baseline: 1.3370x; 1.3370x over previous
//
#include <hip/hip_runtime.h>
#include <stdint.h>

// ---------------------------------------------------------------------------
// SparseResUQueryNet: bitmap+rank sparse conv -> time max-pool -> sparse conv
//
// Round-13 = round-11 verbatim (verified 283.6us: query 110us/VGPR32/occ68%,
// bb_pool 110us/VGPR12/occ80%) + ONE delta:
//   - bijective XCD-chunked blockIdx swizzle in bb_pool_kernel. hcoords is
//     key-sorted, so consecutive blocks probe adjacent hist_bm/rank regions;
//     default round-robin wg->XCD spreads neighbors across 8 private L2s
//     (FETCH 127.5MB vs ~60MB compulsory = 2.5x duplication). Chunked
//     mapping gives each XCD a contiguous key range -> 1/8 working set.
//     query_kernel NOT swizzled (random coords, no inter-block reuse).
// Wave-schedule lessons (r9/r10/r12, three reversions): half-wave-per-point,
// 27-lane parallel bm+rank probe, VGPR<=32 is the floor shape — don't touch.
// ---------------------------------------------------------------------------

#define TPB 256
#define SCAN_WPT 8
typedef unsigned long long u64;
typedef unsigned int u32;
typedef unsigned short u16;

// f32 -> RNE bf16 -> monotone u16 (order-preserving; 0 is below all reals)
__device__ __forceinline__ u32 trans16(float x) {
    u32 b = __float_as_uint(x);
    u32 bf = (b + 0x7FFFu + ((b >> 16) & 1u)) >> 16;
    return ((bf & 0x8000u) ? (~bf) : (bf | 0x8000u)) & 0xFFFFu;
}
__device__ __forceinline__ float detrans16(u32 u) {
    u32 orig = (u & 0x8000u) ? (u & 0x7FFFu) : ((~u) & 0xFFFFu);
    return __uint_as_float(orig << 16);
}

// K1: set existence bits; second pool contributor marks multi ----------------
__global__ void build_bitmaps_kernel(const int4* __restrict__ hc,
                                     const int* __restrict__ hb,
                                     int n,
                                     u64* __restrict__ hist_bm,
                                     u64* __restrict__ pool_bm,
                                     u64* __restrict__ multi_bm) {
    int j = blockIdx.x * blockDim.x + threadIdx.x;
    if (j >= n) return;
    int4 c = hc[j];                                   // (t,x,y,z)
    int key = ((c.x * 256 + c.y) * 256 + c.z) * 256 + c.w;
    atomicOr(&hist_bm[key >> 6], 1ull << (key & 63));
    int pk = ((hb[j] * 256 + c.y) * 256 + c.z) * 256 + c.w;
    u64 bit = 1ull << (pk & 63);
    u64 old = atomicOr(&pool_bm[pk >> 6], bit);
    if (old & bit) atomicOr(&multi_bm[pk >> 6], bit); // >=2 contributors
}

// scan stage 1: per-block popcount sums --------------------------------------
__global__ void scan_sum_kernel(const u64* __restrict__ bm, u32* __restrict__ bsum) {
    __shared__ u32 s[TPB];
    int t = threadIdx.x;
    size_t base = ((size_t)blockIdx.x * TPB + t) * SCAN_WPT;
    u32 acc = 0;
#pragma unroll
    for (int i = 0; i < SCAN_WPT; i++) acc += __popcll(bm[base + i]);
    s[t] = acc; __syncthreads();
    for (int off = TPB / 2; off > 0; off >>= 1) {
        if (t < off) s[t] += s[t + off];
        __syncthreads();
    }
    if (t == 0) bsum[blockIdx.x] = s[0];
}

// scan stage 2: exclusive scan of block sums (count <= 2048), one block ------
__global__ void scan_partials_kernel(u32* __restrict__ bsum, int count) {
    __shared__ u32 s[TPB];
    int t = threadIdx.x;
    int wpt = count >> 8;                              // 8 (hist) or 1 (pool)
    u32 v[8]; u32 acc = 0;
    for (int i = 0; i < wpt; i++) { v[i] = bsum[t * wpt + i]; acc += v[i]; }
    s[t] = acc; __syncthreads();
    for (int off = 1; off < TPB; off <<= 1) {          // inclusive Hillis-Steele
        u32 x = (t >= off) ? s[t - off] : 0;
        __syncthreads();
        s[t] += x;
        __syncthreads();
    }
    u32 run = s[t] - acc;                              // exclusive base
    for (int i = 0; i < wpt; i++) { bsum[t * wpt + i] = run; run += v[i]; }
}

// scan stage 3: per-word exclusive rank --------------------------------------
__global__ void scan_apply_kernel(const u64* __restrict__ bm,
                                  const u32* __restrict__ bsum,
                                  u32* __restrict__ rank) {
    __shared__ u32 s[TPB];
    int t = threadIdx.x;
    size_t base = ((size_t)blockIdx.x * TPB + t) * SCAN_WPT;
    u32 pc[SCAN_WPT]; u32 acc = 0;
#pragma unroll
    for (int i = 0; i < SCAN_WPT; i++) { pc[i] = __popcll(bm[base + i]); acc += pc[i]; }
    s[t] = acc; __syncthreads();
    for (int off = 1; off < TPB; off <<= 1) {
        u32 x = (t >= off) ? s[t - off] : 0;
        __syncthreads();
        s[t] += x;
        __syncthreads();
    }
    u32 run = bsum[blockIdx.x] + s[t] - acc;
#pragma unroll
    for (int i = 0; i < SCAN_WPT; i++) { rank[base + i] = run; run += pc[i]; }
}

// zero only the pooled rows that will take the CAS-max path ------------------
__global__ void zero_multi_kernel(const u64* __restrict__ multi_bm,
                                  const u64* __restrict__ pool_bm,
                                  const u32* __restrict__ pool_rank,
                                  u32* __restrict__ pooled) {
    int wI = blockIdx.x * blockDim.x + threadIdx.x;    // word index < NW_P
    u64 mw = multi_bm[wI];
    if (!mw) return;
    u64 pw = pool_bm[wI];
    u32 rb = pool_rank[wI];
    while (mw) {
        int b = __ffsll((long long)mw) - 1;
        mw &= mw - 1;
        u32 slot = rb + (u32)__popcll(pw & ((1ull << b) - 1ull));
        u32* row = pooled + (size_t)slot * 16;
#pragma unroll
        for (int i = 0; i < 16; i++) row[i] = 0u;
    }
}

// K2: half-wave per voxel: 27-tap conv (1->32) + packed pooled write --------
__global__ __launch_bounds__(TPB, 8)
void bb_pool_kernel(const int4* __restrict__ hc,
                    const int* __restrict__ hb,
                    const float* __restrict__ hf,
                    const float* __restrict__ Wbb,   // [27*32]
                    int n,
                    const u64* __restrict__ hist_bm,
                    const u32* __restrict__ hist_rank,
                    const u64* __restrict__ pool_bm,
                    const u32* __restrict__ pool_rank,
                    const u64* __restrict__ multi_bm,
                    u32* __restrict__ pooled) {
    // XCD-chunked bijective swizzle (m204): wg i lands on XCD i%8; give each
    // XCD a CONTIGUOUS key range so its private L2 holds 1/8 of hist_bm/rank.
    int nwg = gridDim.x;
    int q = nwg >> 3, r = nwg & 7;
    int xcd = blockIdx.x & 7, idx = blockIdx.x >> 3;
    int swz = (xcd < r ? xcd * (q + 1) : r * (q + 1) + (xcd - r) * q) + idx;

    int p = (swz * TPB + threadIdx.x) >> 5;            // voxel index
    if (p >= n) return;
    int lane = threadIdx.x & 63;
    int hb32 = lane & 32;                              // half base within wave
    int f = lane & 31;                                 // feature / tap lane

    int4 c = hc[p];
    int key = ((c.x * 256 + c.y) * 256 + c.z) * 256 + c.w;
    int pk = ((hb[p] * 256 + c.y) * 256 + c.z) * 256 + c.w;

    // pool-side loads issued early (independent of probe chain)
    u64 pword = pool_bm[pk >> 6];
    u32 prank = pool_rank[pk >> 6];
    u64 mword = multi_bm[pk >> 6];

    float fv = 0.f;
    bool hit = false;
    if (f < 27) {
        int t1 = f / 9, rem = f - t1 * 9, t2 = rem / 3, t3 = rem - t2 * 3;
        int nk = key + (t1 - 1) * 65536 + (t2 - 1) * 256 + (t3 - 1);
        u64 word = hist_bm[nk >> 6];                   // parallel independent
        u32 rk   = hist_rank[nk >> 6];                 // loads (overlapped)
        if ((word >> (nk & 63)) & 1ull) {
            u32 r2 = rk + (u32)__popcll(word & ((1ull << (nk & 63)) - 1ull));
            fv = hf[r2];                               // rank == row index j
            hit = true;
        }
    }
    unsigned long long bal = __ballot(hit);
    u32 mymask = (u32)(bal >> hb32);                   // this half's hit taps

    float acc = 0.f;
    while (mymask) {
        int b = __ffs(mymask) - 1;
        mymask &= mymask - 1;
        float fb = __shfl(fv, hb32 + b);               // broadcast neighbor feat
        acc = fmaf(fb, Wbb[b * 32 + f], acc);          // L1-hot 3.4KB table
    }

    int bit = pk & 63;
    int slot = (int)(prank + (u32)__popcll(pword & ((1ull << bit) - 1ull)));
    bool multi = (mword >> bit) & 1ull;

    u32 tv = trans16(acc);
    u32 packed = tv | (((u32)__shfl_down((int)tv, 1)) << 16);  // pair (f, f+1)
    if ((f & 1) == 0) {
        u32* addr = pooled + (size_t)slot * 16 + (f >> 1);
        if (!multi) {
            *addr = packed;                            // ~99%: plain store
        } else {
            u32 oldv = *addr;
            while (true) {
                u32 lo = max(oldv & 0xFFFFu, packed & 0xFFFFu);
                u32 hi = max(oldv >> 16, packed >> 16);
                u32 mx = lo | (hi << 16);
                if (mx == oldv) break;
                u32 prev = atomicCAS(addr, oldv, mx);
                if (prev == oldv) break;
                oldv = prev;
            }
        }
    }
}

// K3: half-wave per query point: 27-tap conv (32->32) + output --------------
__global__ __launch_bounds__(TPB, 8)
void query_kernel(const int4* __restrict__ qc,
                  const float* __restrict__ pts,      // stride 5
                  const float* __restrict__ Wc,       // [27][32][32]
                  int m,
                  const u64* __restrict__ pool_bm,
                  const u32* __restrict__ pool_rank,
                  const u16* __restrict__ pooled16,
                  float* __restrict__ out) {
    int p = (blockIdx.x * blockDim.x + threadIdx.x) >> 5;
    if (p >= m) return;
    int lane = threadIdx.x & 63;
    int hb32 = lane & 32;
    int f = lane & 31;

    int4 c = qc[p];                                    // (b,x,y,z)
    int qk = ((c.x * 256 + c.y) * 256 + c.z) * 256 + c.w;

    int slotL = -1;
    if (f < 27) {
        int t1 = f / 9, rem = f - t1 * 9, t2 = rem / 3, t3 = rem - t2 * 3;
        int nk = qk + (t1 - 1) * 65536 + (t2 - 1) * 256 + (t3 - 1);
        u64 word = pool_bm[nk >> 6];                   // 4MB, mostly L2
        u32 rk   = pool_rank[nk >> 6];                 // 2MB, parallel load
        if ((word >> (nk & 63)) & 1ull)
            slotL = (int)(rk + (u32)__popcll(word & ((1ull << (nk & 63)) - 1ull)));
    }
    unsigned long long bal = __ballot(slotL >= 0);
    u32 mymask = (u32)(bal >> hb32);

    float acc = 0.f;
    while (mymask) {
        int b = __ffs(mymask) - 1;                     // tap index
        mymask &= mymask - 1;
        int slot = __shfl(slotL, hb32 + b);
        float pv = detrans16(pooled16[(size_t)slot * 32 + f]);  // 64B row
        const float* W = Wc + b * 1024 + f;            // W[b][k][f], k-major
#pragma unroll
        for (int k = 0; k < 32; k++) {
            float pk_ = __shfl(pv, hb32 + k);          // broadcast P[k]
            acc = fmaf(pk_, W[k * 32], acc);           // coalesced 128B W line
        }
    }

    // paired float2 stores: 16 store lane-requests instead of 32
    float acc2 = __shfl_down(acc, 1);
    if ((f & 1) == 0) {
        float2 st; st.x = acc; st.y = acc2;
        *(float2*)(out + (size_t)p * 36 + 4 + f) = st;
    }
    if (f < 4) out[(size_t)p * 36 + f] = pts[p * 5 + f];  // head
}

// ---------------------------------------------------------------------------
extern "C" void kernel_launch(void* const* d_in, const int* in_sizes, int n_in,
                              void* d_out, int out_size, void* d_ws, size_t ws_size,
                              hipStream_t stream) {
    const float* hfeat   = (const float*)d_in[0];   // [n,1]
    const float* pts     = (const float*)d_in[1];   // [m,5]
    const float* Wbb     = (const float*)d_in[2];   // [27,1,32]
    const float* Wconv   = (const float*)d_in[3];   // [27,32,32]
    const int4*  hcoords = (const int4*)d_in[4];    // [n,4] sorted by packed key
    const int*   hbatch  = (const int*)d_in[5];     // [n]
    const int4*  qcoords = (const int4*)d_in[6];    // [m,4]
    int n = in_sizes[0];
    int m = in_sizes[1] / 5;

    const int NW_H = 1 << 22;                       // 2^28 bits / 64
    const int NW_P = 1 << 19;                       // 2^25 bits / 64
    const int GB_H = NW_H / (TPB * SCAN_WPT);       // 2048
    const int GB_P = NW_P / (TPB * SCAN_WPT);       // 256

    // layout: [hist_bm | pool_bm | multi_bm] zeroed; pooled NOT zeroed
    char* w = (char*)d_ws;
    char* zbase = w;
    u64* hist_bm      = (u64*)w;       w += (size_t)NW_H * 8;
    u64* pool_bm      = (u64*)w;       w += (size_t)NW_P * 8;
    u64* multi_bm     = (u64*)w;       w += (size_t)NW_P * 8;
    size_t zbytes = (size_t)(w - zbase);
    u32* pooled       = (u32*)w;       w += (size_t)n * 64;      // 16 u32/slot
    u32* hist_rank    = (u32*)w;       w += (size_t)NW_H * 4;
    u32* pool_rank    = (u32*)w;       w += (size_t)NW_P * 4;
    u32* bsum_h       = (u32*)w;       w += (size_t)GB_H * 4;
    u32* bsum_p       = (u32*)w;

    hipMemsetAsync(zbase, 0x00, zbytes, stream);

    int gb_n   = (n + TPB - 1) / TPB;
    int gb_n32 = (int)(((long long)n * 32 + TPB - 1) / TPB);
    int gb_m32 = (int)(((long long)m * 32 + TPB - 1) / TPB);

    build_bitmaps_kernel<<<gb_n, TPB, 0, stream>>>(hcoords, hbatch, n,
                                                   hist_bm, pool_bm, multi_bm);
    scan_sum_kernel<<<GB_H, TPB, 0, stream>>>(hist_bm, bsum_h);
    scan_partials_kernel<<<1, TPB, 0, stream>>>(bsum_h, GB_H);
    scan_apply_kernel<<<GB_H, TPB, 0, stream>>>(hist_bm, bsum_h, hist_rank);
    scan_sum_kernel<<<GB_P, TPB, 0, stream>>>(pool_bm, bsum_p);
    scan_partials_kernel<<<1, TPB, 0, stream>>>(bsum_p, GB_P);
    scan_apply_kernel<<<GB_P, TPB, 0, stream>>>(pool_bm, bsum_p, pool_rank);
    zero_multi_kernel<<<NW_P / TPB, TPB, 0, stream>>>(multi_bm, pool_bm,
                                                      pool_rank, pooled);
    bb_pool_kernel<<<gb_n32, TPB, 0, stream>>>(hcoords, hbatch, hfeat, Wbb, n,
                                               hist_bm, hist_rank,
                                               pool_bm, pool_rank, multi_bm, pooled);
    query_kernel<<<gb_m32, TPB, 0, stream>>>(qcoords, pts, Wconv, m,
                                             pool_bm, pool_rank,
                                             (const u16*)pooled, (float*)d_out);
}

// Round 7
// 262.456 us; speedup vs baseline: 1.4249x; 1.0658x over previous
//
#include <hip/hip_runtime.h>
#include <stdint.h>
#include <utility>

// ---------------------------------------------------------------------------
// SparseResUQueryNet: bitmap+rank sparse conv -> time max-pool -> sparse conv
//
// Round-15 = round-14 with the ds_swizzle constant-offset fix (template
// parameter-pack fold makes each offset a constexpr; builtin requires it):
//   - ONE scan_sum / scan_partials / scan_apply pass covers hist AND pool
//     (blockIdx branch); zero_multi folded into scan_apply's pool branch
//     (words are L1-hot there). 10 dispatches -> 7, -12MB re-read.
//   - query inner k-loop broadcast via __builtin_amdgcn_ds_swizzle
//     (bit-mode or_mask=k: broadcasts lane k within each 32-lane half,
//     no address VGPRs) instead of __shfl (bpermute + addr VALU).
//   - kept: XCD-chunked swizzle in bb_pool (r13), float2 stores, memset cut,
//     27-lane parallel probe, half-wave per point, VGPR<=32.
// Wave-schedule lessons (r9/r10/r12, three reversions): do not touch the
// half-wave-per-point 27-lane-probe shape; VGPR must stay <=32.
// ---------------------------------------------------------------------------

#define TPB 256
#define SCAN_WPT 8
#define GB_H 2048           // hist scan blocks  (NW_H / (TPB*SCAN_WPT))
#define GB_P 256            // pool scan blocks  (NW_P / (TPB*SCAN_WPT))
typedef unsigned long long u64;
typedef unsigned int u32;
typedef unsigned short u16;

// f32 -> RNE bf16 -> monotone u16 (order-preserving; 0 is below all reals)
__device__ __forceinline__ u32 trans16(float x) {
    u32 b = __float_as_uint(x);
    u32 bf = (b + 0x7FFFu + ((b >> 16) & 1u)) >> 16;
    return ((bf & 0x8000u) ? (~bf) : (bf | 0x8000u)) & 0xFFFFu;
}
__device__ __forceinline__ float detrans16(u32 u) {
    u32 orig = (u & 0x8000u) ? (u & 0x7FFFu) : ((~u) & 0xFFFFu);
    return __uint_as_float(orig << 16);
}

// broadcast lane K (within each 32-lane half) of pv, FMA against W[K*32] ----
// ds_swizzle bit-mode offset = (or_mask=K)<<5, and_mask=0, xor=0: every lane
// reads lane K of its 32-lane group. Offset must be a literal constant ->
// template parameter-pack fold.
template <int... Ks>
__device__ __forceinline__ void kfma(float pv, const float* __restrict__ W,
                                     float& acc,
                                     std::integer_sequence<int, Ks...>) {
    ((acc = fmaf(__uint_as_float((u32)__builtin_amdgcn_ds_swizzle(
                     (int)__float_as_uint(pv), (Ks << 5))),
                 W[Ks * 32], acc)),
     ...);
}

// K1: set existence bits; second pool contributor marks multi ----------------
__global__ void build_bitmaps_kernel(const int4* __restrict__ hc,
                                     const int* __restrict__ hb,
                                     int n,
                                     u64* __restrict__ hist_bm,
                                     u64* __restrict__ pool_bm,
                                     u64* __restrict__ multi_bm) {
    int j = blockIdx.x * blockDim.x + threadIdx.x;
    if (j >= n) return;
    int4 c = hc[j];                                   // (t,x,y,z)
    int key = ((c.x * 256 + c.y) * 256 + c.z) * 256 + c.w;
    atomicOr(&hist_bm[key >> 6], 1ull << (key & 63));
    int pk = ((hb[j] * 256 + c.y) * 256 + c.z) * 256 + c.w;
    u64 bit = 1ull << (pk & 63);
    u64 old = atomicOr(&pool_bm[pk >> 6], bit);
    if (old & bit) atomicOr(&multi_bm[pk >> 6], bit); // >=2 contributors
}

// fused scan stage 1: per-block popcount sums, hist then pool ----------------
__global__ void scan_sum_all_kernel(const u64* __restrict__ hist_bm,
                                    const u64* __restrict__ pool_bm,
                                    u32* __restrict__ bsum) {
    __shared__ u32 s[TPB];
    int t = threadIdx.x;
    bool isPool = blockIdx.x >= GB_H;
    const u64* bm = isPool ? pool_bm : hist_bm;
    int blk = isPool ? (blockIdx.x - GB_H) : blockIdx.x;
    size_t base = ((size_t)blk * TPB + t) * SCAN_WPT;
    u32 acc = 0;
#pragma unroll
    for (int i = 0; i < SCAN_WPT; i++) acc += __popcll(bm[base + i]);
    s[t] = acc; __syncthreads();
    for (int off = TPB / 2; off > 0; off >>= 1) {
        if (t < off) s[t] += s[t + off];
        __syncthreads();
    }
    if (t == 0) bsum[blockIdx.x] = s[0];
}

// fused scan stage 2: exclusive scan of hist sums (2048) then pool sums (256)
__global__ void scan_partials_all_kernel(u32* __restrict__ bsum) {
    __shared__ u32 s[TPB];
    int t = threadIdx.x;
    // ---- phase 1: hist block sums [0, 2048), 8 per thread ----
    u32 v[8]; u32 acc = 0;
#pragma unroll
    for (int i = 0; i < 8; i++) { v[i] = bsum[t * 8 + i]; acc += v[i]; }
    s[t] = acc; __syncthreads();
    for (int off = 1; off < TPB; off <<= 1) {          // inclusive Hillis-Steele
        u32 x = (t >= off) ? s[t - off] : 0;
        __syncthreads();
        s[t] += x;
        __syncthreads();
    }
    u32 run = s[t] - acc;                              // exclusive base
#pragma unroll
    for (int i = 0; i < 8; i++) { bsum[t * 8 + i] = run; run += v[i]; }
    __syncthreads();
    // ---- phase 2: pool block sums [GB_H, GB_H+256), 1 per thread ----
    u32 pv = bsum[GB_H + t];
    s[t] = pv; __syncthreads();
    for (int off = 1; off < TPB; off <<= 1) {
        u32 x = (t >= off) ? s[t - off] : 0;
        __syncthreads();
        s[t] += x;
        __syncthreads();
    }
    bsum[GB_H + t] = s[t] - pv;
}

// fused scan stage 3: per-word exclusive rank; pool branch also zeroes the
// pooled rows that will take the CAS-max path (multi bits) -------------------
__global__ void scan_apply_all_kernel(const u64* __restrict__ hist_bm,
                                      const u64* __restrict__ pool_bm,
                                      const u32* __restrict__ bsum,
                                      u32* __restrict__ hist_rank,
                                      u32* __restrict__ pool_rank,
                                      const u64* __restrict__ multi_bm,
                                      u32* __restrict__ pooled) {
    __shared__ u32 s[TPB];
    int t = threadIdx.x;
    bool isPool = blockIdx.x >= GB_H;
    const u64* bm = isPool ? pool_bm : hist_bm;
    u32* rank = isPool ? pool_rank : hist_rank;
    int blk = isPool ? (blockIdx.x - GB_H) : blockIdx.x;
    size_t base = ((size_t)blk * TPB + t) * SCAN_WPT;
    u32 pc[SCAN_WPT]; u32 acc = 0;
#pragma unroll
    for (int i = 0; i < SCAN_WPT; i++) { pc[i] = __popcll(bm[base + i]); acc += pc[i]; }
    s[t] = acc; __syncthreads();
    for (int off = 1; off < TPB; off <<= 1) {
        u32 x = (t >= off) ? s[t - off] : 0;
        __syncthreads();
        s[t] += x;
        __syncthreads();
    }
    u32 run = bsum[blockIdx.x] + s[t] - acc;
    u32 run0 = run;
#pragma unroll
    for (int i = 0; i < SCAN_WPT; i++) { rank[base + i] = run; run += pc[i]; }
    if (isPool) {                                      // fused zero_multi
        u32 r2 = run0;
#pragma unroll
        for (int i = 0; i < SCAN_WPT; i++) {
            u64 mw = multi_bm[base + i];
            if (mw) {
                u64 pw = bm[base + i];                 // L1-hot reload
                while (mw) {
                    int b = __ffsll((long long)mw) - 1;
                    mw &= mw - 1;
                    u32 slot = r2 + (u32)__popcll(pw & ((1ull << b) - 1ull));
                    u32* row = pooled + (size_t)slot * 16;
#pragma unroll
                    for (int w2 = 0; w2 < 16; w2++) row[w2] = 0u;
                }
            }
            r2 += pc[i];
        }
    }
}

// K2: half-wave per voxel: 27-tap conv (1->32) + packed pooled write --------
__global__ __launch_bounds__(TPB, 8)
void bb_pool_kernel(const int4* __restrict__ hc,
                    const int* __restrict__ hb,
                    const float* __restrict__ hf,
                    const float* __restrict__ Wbb,   // [27*32]
                    int n,
                    const u64* __restrict__ hist_bm,
                    const u32* __restrict__ hist_rank,
                    const u64* __restrict__ pool_bm,
                    const u32* __restrict__ pool_rank,
                    const u64* __restrict__ multi_bm,
                    u32* __restrict__ pooled) {
    // XCD-chunked bijective swizzle (r13, verified): contiguous key range per
    // XCD so its private L2 holds 1/8 of hist_bm/rank.
    int nwg = gridDim.x;
    int q = nwg >> 3, r = nwg & 7;
    int xcd = blockIdx.x & 7, idx = blockIdx.x >> 3;
    int swz = (xcd < r ? xcd * (q + 1) : r * (q + 1) + (xcd - r) * q) + idx;

    int p = (swz * TPB + threadIdx.x) >> 5;            // voxel index
    if (p >= n) return;
    int lane = threadIdx.x & 63;
    int hb32 = lane & 32;                              // half base within wave
    int f = lane & 31;                                 // feature / tap lane

    int4 c = hc[p];
    int key = ((c.x * 256 + c.y) * 256 + c.z) * 256 + c.w;
    int pk = ((hb[p] * 256 + c.y) * 256 + c.z) * 256 + c.w;

    // pool-side loads issued early (independent of probe chain)
    u64 pword = pool_bm[pk >> 6];
    u32 prank = pool_rank[pk >> 6];
    u64 mword = multi_bm[pk >> 6];

    float fv = 0.f;
    bool hit = false;
    if (f < 27) {
        int t1 = f / 9, rem = f - t1 * 9, t2 = rem / 3, t3 = rem - t2 * 3;
        int nk = key + (t1 - 1) * 65536 + (t2 - 1) * 256 + (t3 - 1);
        u64 word = hist_bm[nk >> 6];                   // parallel independent
        u32 rk   = hist_rank[nk >> 6];                 // loads (overlapped)
        if ((word >> (nk & 63)) & 1ull) {
            u32 r2 = rk + (u32)__popcll(word & ((1ull << (nk & 63)) - 1ull));
            fv = hf[r2];                               // rank == row index j
            hit = true;
        }
    }
    unsigned long long bal = __ballot(hit);
    u32 mymask = (u32)(bal >> hb32);                   // this half's hit taps

    float acc = 0.f;
    while (mymask) {
        int b = __ffs(mymask) - 1;
        mymask &= mymask - 1;
        float fb = __shfl(fv, hb32 + b);               // broadcast neighbor feat
        acc = fmaf(fb, Wbb[b * 32 + f], acc);          // L1-hot 3.4KB table
    }

    int bit = pk & 63;
    int slot = (int)(prank + (u32)__popcll(pword & ((1ull << bit) - 1ull)));
    bool multi = (mword >> bit) & 1ull;

    u32 tv = trans16(acc);
    u32 packed = tv | (((u32)__shfl_down((int)tv, 1)) << 16);  // pair (f, f+1)
    if ((f & 1) == 0) {
        u32* addr = pooled + (size_t)slot * 16 + (f >> 1);
        if (!multi) {
            *addr = packed;                            // ~99%: plain store
        } else {
            u32 oldv = *addr;
            while (true) {
                u32 lo = max(oldv & 0xFFFFu, packed & 0xFFFFu);
                u32 hi = max(oldv >> 16, packed >> 16);
                u32 mx = lo | (hi << 16);
                if (mx == oldv) break;
                u32 prev = atomicCAS(addr, oldv, mx);
                if (prev == oldv) break;
                oldv = prev;
            }
        }
    }
}

// K3: half-wave per query point: 27-tap conv (32->32) + output --------------
__global__ __launch_bounds__(TPB, 8)
void query_kernel(const int4* __restrict__ qc,
                  const float* __restrict__ pts,      // stride 5
                  const float* __restrict__ Wc,       // [27][32][32]
                  int m,
                  const u64* __restrict__ pool_bm,
                  const u32* __restrict__ pool_rank,
                  const u16* __restrict__ pooled16,
                  float* __restrict__ out) {
    int p = (blockIdx.x * blockDim.x + threadIdx.x) >> 5;
    if (p >= m) return;
    int lane = threadIdx.x & 63;
    int hb32 = lane & 32;
    int f = lane & 31;

    int4 c = qc[p];                                    // (b,x,y,z)
    int qk = ((c.x * 256 + c.y) * 256 + c.z) * 256 + c.w;

    int slotL = -1;
    if (f < 27) {
        int t1 = f / 9, rem = f - t1 * 9, t2 = rem / 3, t3 = rem - t2 * 3;
        int nk = qk + (t1 - 1) * 65536 + (t2 - 1) * 256 + (t3 - 1);
        u64 word = pool_bm[nk >> 6];                   // 4MB, mostly L2
        u32 rk   = pool_rank[nk >> 6];                 // 2MB, parallel load
        if ((word >> (nk & 63)) & 1ull)
            slotL = (int)(rk + (u32)__popcll(word & ((1ull << (nk & 63)) - 1ull)));
    }
    unsigned long long bal = __ballot(slotL >= 0);
    u32 mymask = (u32)(bal >> hb32);

    float acc = 0.f;
    while (mymask) {
        int b = __ffs(mymask) - 1;                     // tap index
        mymask &= mymask - 1;
        int slot = __shfl(slotL, hb32 + b);
        float pv = detrans16(pooled16[(size_t)slot * 32 + f]);  // 64B row
        const float* W = Wc + b * 1024 + f;            // W[b][k][f], k-major
        // 32 constant-offset ds_swizzle broadcasts (lane k of each half),
        // no address VGPRs, coalesced 128B W lines:
        kfma(pv, W, acc, std::make_integer_sequence<int, 32>{});
    }

    // paired float2 stores: 16 store lane-requests instead of 32
    float acc2 = __shfl_down(acc, 1);
    if ((f & 1) == 0) {
        float2 st; st.x = acc; st.y = acc2;
        *(float2*)(out + (size_t)p * 36 + 4 + f) = st;
    }
    if (f < 4) out[(size_t)p * 36 + f] = pts[p * 5 + f];  // head
}

// ---------------------------------------------------------------------------
extern "C" void kernel_launch(void* const* d_in, const int* in_sizes, int n_in,
                              void* d_out, int out_size, void* d_ws, size_t ws_size,
                              hipStream_t stream) {
    const float* hfeat   = (const float*)d_in[0];   // [n,1]
    const float* pts     = (const float*)d_in[1];   // [m,5]
    const float* Wbb     = (const float*)d_in[2];   // [27,1,32]
    const float* Wconv   = (const float*)d_in[3];   // [27,32,32]
    const int4*  hcoords = (const int4*)d_in[4];    // [n,4] sorted by packed key
    const int*   hbatch  = (const int*)d_in[5];     // [n]
    const int4*  qcoords = (const int4*)d_in[6];    // [m,4]
    int n = in_sizes[0];
    int m = in_sizes[1] / 5;

    const int NW_H = 1 << 22;                       // 2^28 bits / 64
    const int NW_P = 1 << 19;                       // 2^25 bits / 64

    // layout: [hist_bm | pool_bm | multi_bm] zeroed; pooled NOT zeroed
    char* w = (char*)d_ws;
    char* zbase = w;
    u64* hist_bm      = (u64*)w;       w += (size_t)NW_H * 8;
    u64* pool_bm      = (u64*)w;       w += (size_t)NW_P * 8;
    u64* multi_bm     = (u64*)w;       w += (size_t)NW_P * 8;
    size_t zbytes = (size_t)(w - zbase);
    u32* pooled       = (u32*)w;       w += (size_t)n * 64;      // 16 u32/slot
    u32* hist_rank    = (u32*)w;       w += (size_t)NW_H * 4;
    u32* pool_rank    = (u32*)w;       w += (size_t)NW_P * 4;
    u32* bsum         = (u32*)w;       w += (size_t)(GB_H + GB_P) * 4;

    hipMemsetAsync(zbase, 0x00, zbytes, stream);

    int gb_n   = (n + TPB - 1) / TPB;
    int gb_n32 = (int)(((long long)n * 32 + TPB - 1) / TPB);
    int gb_m32 = (int)(((long long)m * 32 + TPB - 1) / TPB);

    build_bitmaps_kernel<<<gb_n, TPB, 0, stream>>>(hcoords, hbatch, n,
                                                   hist_bm, pool_bm, multi_bm);
    scan_sum_all_kernel<<<GB_H + GB_P, TPB, 0, stream>>>(hist_bm, pool_bm, bsum);
    scan_partials_all_kernel<<<1, TPB, 0, stream>>>(bsum);
    scan_apply_all_kernel<<<GB_H + GB_P, TPB, 0, stream>>>(hist_bm, pool_bm, bsum,
                                                           hist_rank, pool_rank,
                                                           multi_bm, pooled);
    bb_pool_kernel<<<gb_n32, TPB, 0, stream>>>(hcoords, hbatch, hfeat, Wbb, n,
                                               hist_bm, hist_rank,
                                               pool_bm, pool_rank, multi_bm, pooled);
    query_kernel<<<gb_m32, TPB, 0, stream>>>(qcoords, pts, Wconv, m,
                                             pool_bm, pool_rank,
                                             (const u16*)pooled, (float*)d_out);
}